// Round 1
// baseline (591.804 us; speedup 1.0000x reference)
//
#include <hip/hip_runtime.h>
#include <cstdint>

#define N_NODES 50000
#define N_EDGES 1600000
#define IN_DIM 128
#define HID_DIM 128
#define OUT_DIM 64

// ---------------- degree counting ----------------
__global__ void gcn_deg_kernel(const int* __restrict__ src, const int* __restrict__ dst,
                               unsigned int* __restrict__ outdeg, unsigned int* __restrict__ indeg) {
    int e = blockIdx.x * 256 + threadIdx.x;
    if (e < N_EDGES) {
        atomicAdd(&outdeg[src[e]], 1u);
        atomicAdd(&indeg[dst[e]], 1u);
    }
}

__global__ void gcn_norm_kernel(const unsigned int* __restrict__ outdeg,
                                const unsigned int* __restrict__ indeg,
                                float* __restrict__ on, float* __restrict__ inn) {
    int i = blockIdx.x * 256 + threadIdx.x;
    if (i < N_NODES) {
        unsigned int od = outdeg[i]; if (od < 1u) od = 1u;
        unsigned int id = indeg[i];  if (id < 1u) id = 1u;
        on[i]  = rsqrtf((float)od);
        inn[i] = rsqrtf((float)id);
    }
}

// ---------------- exclusive scan (3 kernels) ----------------
__global__ void gcn_scan1_kernel(const unsigned int* __restrict__ in, unsigned int* __restrict__ out,
                                 unsigned int* __restrict__ blk, int n) {
    __shared__ unsigned int s[256];
    int tid = threadIdx.x;
    int i = blockIdx.x * 256 + tid;
    unsigned int v = (i < n) ? in[i] : 0u;
    s[tid] = v;
    __syncthreads();
    for (int off = 1; off < 256; off <<= 1) {
        unsigned int t = (tid >= off) ? s[tid - off] : 0u;
        __syncthreads();
        s[tid] += t;
        __syncthreads();
    }
    if (i < n) out[i] = s[tid] - v;  // exclusive
    if (tid == 255) blk[blockIdx.x] = s[255];
}

__global__ void gcn_scan2_kernel(const unsigned int* __restrict__ blk, unsigned int* __restrict__ blkoff, int nblk) {
    __shared__ unsigned int s[256];
    int tid = threadIdx.x;
    unsigned int v = (tid < nblk) ? blk[tid] : 0u;
    s[tid] = v;
    __syncthreads();
    for (int off = 1; off < 256; off <<= 1) {
        unsigned int t = (tid >= off) ? s[tid - off] : 0u;
        __syncthreads();
        s[tid] += t;
        __syncthreads();
    }
    blkoff[tid] = s[tid] - v;
}

__global__ void gcn_scan3_kernel(unsigned int* __restrict__ row_ptr, unsigned int* __restrict__ cursor,
                                 const unsigned int* __restrict__ blkoff, int n) {
    int i = blockIdx.x * 256 + threadIdx.x;
    if (i < n) {
        unsigned int r = row_ptr[i] + blkoff[blockIdx.x];
        row_ptr[i] = r;
        cursor[i] = r;
    }
    if (i == 0) row_ptr[n] = N_EDGES;
}

__global__ void gcn_fill_kernel(const int* __restrict__ src, const int* __restrict__ dst,
                                unsigned int* __restrict__ cursor, int* __restrict__ csr_src) {
    int e = blockIdx.x * 256 + threadIdx.x;
    if (e < N_EDGES) {
        unsigned int pos = atomicAdd(&cursor[dst[e]], 1u);
        csr_src[pos] = src[e];
    }
}

// ---------------- GEMM1: h = (x * on[:,None]) @ W1  (128 -> 128) ----------------
__global__ void gcn_gemm1_kernel(const float* __restrict__ x, const float* __restrict__ on,
                                 const float* __restrict__ W, float* __restrict__ h) {
    __shared__ float4 Ws[128 * 32];      // 64 KiB, W[k][j] as float4 over j
    __shared__ float  xs[4][132];        // padded to avoid 4-way bank conflict
    int tid = threadIdx.x;               // 128 threads
    for (int i = tid; i < 128 * 32; i += 128) Ws[i] = ((const float4*)W)[i];

    int ns = tid >> 5;   // 0..3  node sub-index
    int jg = tid & 31;   // 0..31 float4 group over 128 outputs
    int ngroups = (N_NODES + 3) / 4;
    for (int g = blockIdx.x; g < ngroups; g += gridDim.x) {
        int n0 = g * 4;
        __syncthreads();   // protect xs (and Ws on first iter) before overwrite
        for (int i = tid; i < 4 * 128; i += 128) {
            int s = i >> 7, k = i & 127;
            int nn = n0 + s;
            xs[s][k] = (nn < N_NODES) ? x[(size_t)nn * 128 + k] * on[nn] : 0.f;
        }
        __syncthreads();
        float4 acc = {0.f, 0.f, 0.f, 0.f};
        #pragma unroll 4
        for (int k = 0; k < 128; ++k) {
            float xk = xs[ns][k];
            float4 w = Ws[k * 32 + jg];
            acc.x += xk * w.x; acc.y += xk * w.y; acc.z += xk * w.z; acc.w += xk * w.w;
        }
        int n = n0 + ns;
        if (n < N_NODES) ((float4*)h)[(size_t)n * 32 + jg] = acc;
    }
}

// ---------------- agg1: h1 = relu(segsum(h[src]) * inn + b1) ----------------
__global__ void gcn_agg1_kernel(const float* __restrict__ h, const int* __restrict__ csr,
                                const unsigned int* __restrict__ row_ptr,
                                const float* __restrict__ inn, const float* __restrict__ b1,
                                float* __restrict__ h1) {
    int n = blockIdx.x;
    int tid = threadIdx.x;  // 128
    unsigned int beg = row_ptr[n], end = row_ptr[n + 1];
    __shared__ int es[128];
    float acc = 0.f;
    for (unsigned int base = beg; base < end; base += 128) {
        unsigned int cnt = end - base; if (cnt > 128u) cnt = 128u;
        if (tid < (int)cnt) es[tid] = csr[base + tid];
        __syncthreads();
        for (unsigned int i = 0; i < cnt; ++i) {
            acc += h[(size_t)es[i] * 128 + tid];
        }
        __syncthreads();
    }
    float v = acc * inn[n] + b1[tid];
    h1[(size_t)n * 128 + tid] = fmaxf(v, 0.f);
}

// ---------------- GEMM2: h2 = (h1 * on[:,None]) @ W2  (128 -> 64) ----------------
__global__ void gcn_gemm2_kernel(const float* __restrict__ h1, const float* __restrict__ on,
                                 const float* __restrict__ W, float* __restrict__ h2) {
    __shared__ float4 Ws[128 * 16];      // 32 KiB
    __shared__ float  xs[8][132];
    int tid = threadIdx.x;               // 128 threads
    for (int i = tid; i < 128 * 16; i += 128) Ws[i] = ((const float4*)W)[i];

    int ns = tid >> 4;   // 0..7
    int jg = tid & 15;   // 0..15 float4 group over 64 outputs
    int ngroups = (N_NODES + 7) / 8;
    for (int g = blockIdx.x; g < ngroups; g += gridDim.x) {
        int n0 = g * 8;
        __syncthreads();
        for (int i = tid; i < 8 * 128; i += 128) {
            int s = i >> 7, k = i & 127;
            int nn = n0 + s;
            xs[s][k] = (nn < N_NODES) ? h1[(size_t)nn * 128 + k] * on[nn] : 0.f;
        }
        __syncthreads();
        float4 acc = {0.f, 0.f, 0.f, 0.f};
        #pragma unroll 4
        for (int k = 0; k < 128; ++k) {
            float xk = xs[ns][k];
            float4 w = Ws[k * 16 + jg];
            acc.x += xk * w.x; acc.y += xk * w.y; acc.z += xk * w.z; acc.w += xk * w.w;
        }
        int n = n0 + ns;
        if (n < N_NODES) ((float4*)h2)[(size_t)n * 16 + jg] = acc;
    }
}

// ---------------- agg2: out = segsum(h2[src]) * inn + b2 ----------------
__global__ void gcn_agg2_kernel(const float* __restrict__ h2, const int* __restrict__ csr,
                                const unsigned int* __restrict__ row_ptr,
                                const float* __restrict__ inn, const float* __restrict__ b2,
                                float* __restrict__ out) {
    int n = blockIdx.x;
    int tid = threadIdx.x;  // 64
    unsigned int beg = row_ptr[n], end = row_ptr[n + 1];
    __shared__ int es[64];
    float acc = 0.f;
    for (unsigned int base = beg; base < end; base += 64) {
        unsigned int cnt = end - base; if (cnt > 64u) cnt = 64u;
        if (tid < (int)cnt) es[tid] = csr[base + tid];
        __syncthreads();
        for (unsigned int i = 0; i < cnt; ++i) {
            acc += h2[(size_t)es[i] * 64 + tid];
        }
        __syncthreads();
    }
    out[(size_t)n * 64 + tid] = acc * inn[n] + b2[tid];
}

extern "C" void kernel_launch(void* const* d_in, const int* in_sizes, int n_in,
                              void* d_out, int out_size, void* d_ws, size_t ws_size,
                              hipStream_t stream) {
    const float* x  = (const float*)d_in[0];
    const float* W1 = (const float*)d_in[1];
    const float* b1 = (const float*)d_in[2];
    const float* W2 = (const float*)d_in[3];
    const float* b2 = (const float*)d_in[4];
    const int*   src = (const int*)d_in[5];
    const int*   dst = (const int*)d_in[6];
    float* out = (float*)d_out;

    char* ws = (char*)d_ws;
    size_t off = 0;
    auto alloc = [&](size_t bytes) -> void* {
        void* p = ws + off;
        off += (bytes + 255) & ~(size_t)255;
        return p;
    };

    unsigned int* outdeg  = (unsigned int*)alloc((size_t)N_NODES * 4);
    unsigned int* indeg   = (unsigned int*)alloc((size_t)N_NODES * 4);
    float*        on      = (float*)alloc((size_t)N_NODES * 4);
    float*        inn     = (float*)alloc((size_t)N_NODES * 4);
    unsigned int* row_ptr = (unsigned int*)alloc((size_t)(N_NODES + 1) * 4);
    unsigned int* cursor  = (unsigned int*)alloc((size_t)N_NODES * 4);
    unsigned int* blksum  = (unsigned int*)alloc(256 * 4);
    unsigned int* blkoff  = (unsigned int*)alloc(256 * 4);
    int*          csr     = (int*)alloc((size_t)N_EDGES * 4);
    float*        h       = (float*)alloc((size_t)N_NODES * 128 * 4);   // reused as h2
    float*        h1      = (float*)alloc((size_t)N_NODES * 128 * 4);
    float*        h2      = h;   // h dead after agg1

    int nblk_nodes = (N_NODES + 255) / 256;   // 196
    int nblk_edges = (N_EDGES + 255) / 256;   // 6250

    hipMemsetAsync(outdeg, 0, (size_t)N_NODES * 4, stream);
    hipMemsetAsync(indeg,  0, (size_t)N_NODES * 4, stream);

    gcn_deg_kernel<<<nblk_edges, 256, 0, stream>>>(src, dst, outdeg, indeg);
    gcn_norm_kernel<<<nblk_nodes, 256, 0, stream>>>(outdeg, indeg, on, inn);
    gcn_scan1_kernel<<<nblk_nodes, 256, 0, stream>>>(indeg, row_ptr, blksum, N_NODES);
    gcn_scan2_kernel<<<1, 256, 0, stream>>>(blksum, blkoff, nblk_nodes);
    gcn_scan3_kernel<<<nblk_nodes, 256, 0, stream>>>(row_ptr, cursor, blkoff, N_NODES);
    gcn_fill_kernel<<<nblk_edges, 256, 0, stream>>>(src, dst, cursor, csr);

    gcn_gemm1_kernel<<<512, 128, 0, stream>>>(x, on, W1, h);
    gcn_agg1_kernel<<<N_NODES, 128, 0, stream>>>(h, csr, row_ptr, inn, b1, h1);
    gcn_gemm2_kernel<<<512, 128, 0, stream>>>(h1, on, W2, h2);
    gcn_agg2_kernel<<<N_NODES, 64, 0, stream>>>(h2, csr, row_ptr, inn, b2, out);
}

// Round 2
// 446.181 us; speedup vs baseline: 1.3264x; 1.3264x over previous
//
#include <hip/hip_runtime.h>
#include <cstdint>

#define N_NODES 50000
#define N_EDGES 1600000

// threads covering edges with 4-way ILP: 1563 blocks * 256 = 400128
#define EDGE_T 400128

// ---------------- indeg counting (4-way ILP) ----------------
__global__ void gcn_degi_kernel(const int* __restrict__ dst, unsigned int* __restrict__ indeg) {
    int t = blockIdx.x * 256 + threadIdx.x;
    int d[4]; bool v[4];
    #pragma unroll
    for (int j = 0; j < 4; ++j) {
        int e = t + j * EDGE_T;
        v[j] = e < N_EDGES;
        d[j] = v[j] ? dst[e] : 0;
    }
    #pragma unroll
    for (int j = 0; j < 4; ++j)
        if (v[j]) atomicAdd(&indeg[d[j]], 1u);
}

__global__ void gcn_norm_kernel(const unsigned int* __restrict__ outdeg,
                                const unsigned int* __restrict__ indeg,
                                float* __restrict__ on, float* __restrict__ inn) {
    int i = blockIdx.x * 256 + threadIdx.x;
    if (i < N_NODES) {
        unsigned int od = outdeg[i]; if (od < 1u) od = 1u;
        unsigned int id = indeg[i];  if (id < 1u) id = 1u;
        on[i]  = rsqrtf((float)od);
        inn[i] = rsqrtf((float)id);
    }
}

// ---------------- exclusive scan (3 kernels) ----------------
__global__ void gcn_scan1_kernel(const unsigned int* __restrict__ in, unsigned int* __restrict__ out,
                                 unsigned int* __restrict__ blk, int n) {
    __shared__ unsigned int s[256];
    int tid = threadIdx.x;
    int i = blockIdx.x * 256 + tid;
    unsigned int v = (i < n) ? in[i] : 0u;
    s[tid] = v;
    __syncthreads();
    for (int off = 1; off < 256; off <<= 1) {
        unsigned int t = (tid >= off) ? s[tid - off] : 0u;
        __syncthreads();
        s[tid] += t;
        __syncthreads();
    }
    if (i < n) out[i] = s[tid] - v;  // exclusive
    if (tid == 255) blk[blockIdx.x] = s[255];
}

__global__ void gcn_scan2_kernel(const unsigned int* __restrict__ blk, unsigned int* __restrict__ blkoff, int nblk) {
    __shared__ unsigned int s[256];
    int tid = threadIdx.x;
    unsigned int v = (tid < nblk) ? blk[tid] : 0u;
    s[tid] = v;
    __syncthreads();
    for (int off = 1; off < 256; off <<= 1) {
        unsigned int t = (tid >= off) ? s[tid - off] : 0u;
        __syncthreads();
        s[tid] += t;
        __syncthreads();
    }
    blkoff[tid] = s[tid] - v;
}

__global__ void gcn_scan3_kernel(unsigned int* __restrict__ row_ptr, unsigned int* __restrict__ cursor,
                                 const unsigned int* __restrict__ blkoff, int n) {
    int i = blockIdx.x * 256 + threadIdx.x;
    if (i < n) {
        unsigned int r = row_ptr[i] + blkoff[blockIdx.x];
        row_ptr[i] = r;
        cursor[i] = r;
    }
    if (i == 0) row_ptr[n] = N_EDGES;
}

// ---------------- CSR fill + outdeg (4-way ILP) ----------------
__global__ void gcn_fill_kernel(const int* __restrict__ src, const int* __restrict__ dst,
                                unsigned int* __restrict__ cursor, unsigned int* __restrict__ outdeg,
                                int* __restrict__ csr_src) {
    int t = blockIdx.x * 256 + threadIdx.x;
    int s[4], d[4]; bool v[4];
    #pragma unroll
    for (int j = 0; j < 4; ++j) {
        int e = t + j * EDGE_T;
        v[j] = e < N_EDGES;
        s[j] = v[j] ? src[e] : 0;
        d[j] = v[j] ? dst[e] : 0;
    }
    unsigned int p[4];
    #pragma unroll
    for (int j = 0; j < 4; ++j)
        if (v[j]) p[j] = atomicAdd(&cursor[d[j]], 1u);
    #pragma unroll
    for (int j = 0; j < 4; ++j)
        if (v[j]) { csr_src[p[j]] = s[j]; atomicAdd(&outdeg[s[j]], 1u); }
}

// ---------------- GEMM helpers ----------------
#define FMA4(A, S, WV) { (A).x += (S)*(WV).x; (A).y += (S)*(WV).y; (A).z += (S)*(WV).z; (A).w += (S)*(WV).w; }

// GEMM1: h = (x * on[:,None]) @ W1  (50000x128 @ 128x128), j-half per block
__global__ __launch_bounds__(256, 4) void gcn_gemm1_kernel(
        const float* __restrict__ x, const float* __restrict__ on,
        const float* __restrict__ W, float* __restrict__ h) {
    __shared__ float4 Ws[128 * 16];      // 32 KiB: half of W's columns
    int tid = threadIdx.x;
    int tile = blockIdx.x >> 1, half = blockIdx.x & 1;
    for (int i = tid; i < 128 * 16; i += 256) {
        int k = i >> 4, q = i & 15;
        Ws[i] = ((const float4*)W)[k * 32 + half * 16 + q];
    }
    __syncthreads();

    int jg = tid & 15;        // float4 group within the 64-output half
    int ns = tid >> 4;        // 0..15
    int n0 = tile * 64 + ns * 4;

    float sc[4]; bool val[4];
    float4 acc[4];
    #pragma unroll
    for (int i = 0; i < 4; ++i) {
        int n = n0 + i; val[i] = (n < N_NODES);
        sc[i] = val[i] ? on[n] : 0.f;
        acc[i] = float4{0.f, 0.f, 0.f, 0.f};
    }

    const float4* xv4 = (const float4*)x;
    float4 xc[4], wc[4], xn[4], wn[4];
    #pragma unroll
    for (int i = 0; i < 4; ++i)
        xc[i] = val[i] ? xv4[(size_t)(n0 + i) * 32] : float4{0.f, 0.f, 0.f, 0.f};
    #pragma unroll
    for (int t = 0; t < 4; ++t) wc[t] = Ws[t * 16 + jg];

    for (int kc = 0; kc < 32; ++kc) {
        if (kc < 31) {
            #pragma unroll
            for (int i = 0; i < 4; ++i)
                xn[i] = val[i] ? xv4[(size_t)(n0 + i) * 32 + kc + 1] : float4{0.f, 0.f, 0.f, 0.f};
            #pragma unroll
            for (int t = 0; t < 4; ++t) wn[t] = Ws[(kc * 4 + 4 + t) * 16 + jg];
        }
        #pragma unroll
        for (int i = 0; i < 4; ++i) {
            FMA4(acc[i], xc[i].x, wc[0]);
            FMA4(acc[i], xc[i].y, wc[1]);
            FMA4(acc[i], xc[i].z, wc[2]);
            FMA4(acc[i], xc[i].w, wc[3]);
        }
        #pragma unroll
        for (int i = 0; i < 4; ++i) xc[i] = xn[i];
        #pragma unroll
        for (int t = 0; t < 4; ++t) wc[t] = wn[t];
    }
    #pragma unroll
    for (int i = 0; i < 4; ++i) {
        if (val[i]) {
            acc[i].x *= sc[i]; acc[i].y *= sc[i]; acc[i].z *= sc[i]; acc[i].w *= sc[i];
            ((float4*)h)[(size_t)(n0 + i) * 32 + half * 16 + jg] = acc[i];
        }
    }
}

// GEMM2: h2 = (h1 * on[:,None]) @ W2  (50000x128 @ 128x64)
__global__ __launch_bounds__(256, 4) void gcn_gemm2_kernel(
        const float* __restrict__ h1, const float* __restrict__ on,
        const float* __restrict__ W, float* __restrict__ h2) {
    __shared__ float4 Ws[128 * 16];      // 32 KiB: all of W2
    int tid = threadIdx.x;
    int tile = blockIdx.x;
    for (int i = tid; i < 128 * 16; i += 256) Ws[i] = ((const float4*)W)[i];
    __syncthreads();

    int jg = tid & 15;        // float4 group over 64 outputs
    int ns = tid >> 4;        // 0..15
    int n0 = tile * 64 + ns * 4;

    float sc[4]; bool val[4];
    float4 acc[4];
    #pragma unroll
    for (int i = 0; i < 4; ++i) {
        int n = n0 + i; val[i] = (n < N_NODES);
        sc[i] = val[i] ? on[n] : 0.f;
        acc[i] = float4{0.f, 0.f, 0.f, 0.f};
    }

    const float4* xv4 = (const float4*)h1;
    float4 xc[4], wc[4], xn[4], wn[4];
    #pragma unroll
    for (int i = 0; i < 4; ++i)
        xc[i] = val[i] ? xv4[(size_t)(n0 + i) * 32] : float4{0.f, 0.f, 0.f, 0.f};
    #pragma unroll
    for (int t = 0; t < 4; ++t) wc[t] = Ws[t * 16 + jg];

    for (int kc = 0; kc < 32; ++kc) {
        if (kc < 31) {
            #pragma unroll
            for (int i = 0; i < 4; ++i)
                xn[i] = val[i] ? xv4[(size_t)(n0 + i) * 32 + kc + 1] : float4{0.f, 0.f, 0.f, 0.f};
            #pragma unroll
            for (int t = 0; t < 4; ++t) wn[t] = Ws[(kc * 4 + 4 + t) * 16 + jg];
        }
        #pragma unroll
        for (int i = 0; i < 4; ++i) {
            FMA4(acc[i], xc[i].x, wc[0]);
            FMA4(acc[i], xc[i].y, wc[1]);
            FMA4(acc[i], xc[i].z, wc[2]);
            FMA4(acc[i], xc[i].w, wc[3]);
        }
        #pragma unroll
        for (int i = 0; i < 4; ++i) xc[i] = xn[i];
        #pragma unroll
        for (int t = 0; t < 4; ++t) wc[t] = wn[t];
    }
    #pragma unroll
    for (int i = 0; i < 4; ++i) {
        if (val[i]) {
            acc[i].x *= sc[i]; acc[i].y *= sc[i]; acc[i].z *= sc[i]; acc[i].w *= sc[i];
            ((float4*)h2)[(size_t)(n0 + i) * 16 + jg] = acc[i];
        }
    }
}

// ---------------- agg1: h1 = relu(segsum(h[src]) * inn + b1) ----------------
__global__ void gcn_agg1_kernel(const float* __restrict__ h, const int* __restrict__ csr,
                                const unsigned int* __restrict__ row_ptr,
                                const float* __restrict__ inn, const float* __restrict__ b1,
                                float* __restrict__ h1) {
    int n = blockIdx.x;
    int tid = threadIdx.x;  // 128
    unsigned int beg = row_ptr[n], end = row_ptr[n + 1];
    __shared__ int es[128];
    float acc = 0.f;
    for (unsigned int base = beg; base < end; base += 128) {
        unsigned int cnt = end - base; if (cnt > 128u) cnt = 128u;
        if (tid < (int)cnt) es[tid] = csr[base + tid];
        __syncthreads();
        for (unsigned int i = 0; i < cnt; ++i) {
            acc += h[(size_t)es[i] * 128 + tid];
        }
        __syncthreads();
    }
    float v = acc * inn[n] + b1[tid];
    h1[(size_t)n * 128 + tid] = fmaxf(v, 0.f);
}

// ---------------- agg2: out = segsum(h2[src]) * inn + b2 ----------------
__global__ void gcn_agg2_kernel(const float* __restrict__ h2, const int* __restrict__ csr,
                                const unsigned int* __restrict__ row_ptr,
                                const float* __restrict__ inn, const float* __restrict__ b2,
                                float* __restrict__ out) {
    int n = blockIdx.x;
    int tid = threadIdx.x;  // 64
    unsigned int beg = row_ptr[n], end = row_ptr[n + 1];
    __shared__ int es[64];
    float acc = 0.f;
    for (unsigned int base = beg; base < end; base += 64) {
        unsigned int cnt = end - base; if (cnt > 64u) cnt = 64u;
        if (tid < (int)cnt) es[tid] = csr[base + tid];
        __syncthreads();
        for (unsigned int i = 0; i < cnt; ++i) {
            acc += h2[(size_t)es[i] * 64 + tid];
        }
        __syncthreads();
    }
    out[(size_t)n * 64 + tid] = acc * inn[n] + b2[tid];
}

extern "C" void kernel_launch(void* const* d_in, const int* in_sizes, int n_in,
                              void* d_out, int out_size, void* d_ws, size_t ws_size,
                              hipStream_t stream) {
    const float* x  = (const float*)d_in[0];
    const float* W1 = (const float*)d_in[1];
    const float* b1 = (const float*)d_in[2];
    const float* W2 = (const float*)d_in[3];
    const float* b2 = (const float*)d_in[4];
    const int*   src = (const int*)d_in[5];
    const int*   dst = (const int*)d_in[6];
    float* out = (float*)d_out;

    char* ws = (char*)d_ws;
    size_t off = 0;
    auto alloc = [&](size_t bytes) -> void* {
        void* p = ws + off;
        off += (bytes + 255) & ~(size_t)255;
        return p;
    };

    unsigned int* outdeg  = (unsigned int*)alloc((size_t)N_NODES * 4);
    unsigned int* indeg   = (unsigned int*)alloc((size_t)N_NODES * 4);
    float*        on      = (float*)alloc((size_t)N_NODES * 4);
    float*        inn     = (float*)alloc((size_t)N_NODES * 4);
    unsigned int* row_ptr = (unsigned int*)alloc((size_t)(N_NODES + 1) * 4);
    unsigned int* cursor  = (unsigned int*)alloc((size_t)N_NODES * 4);
    unsigned int* blksum  = (unsigned int*)alloc(256 * 4);
    unsigned int* blkoff  = (unsigned int*)alloc(256 * 4);
    int*          csr     = (int*)alloc((size_t)N_EDGES * 4);
    float*        h       = (float*)alloc((size_t)N_NODES * 128 * 4);   // reused as h2
    float*        h1      = (float*)alloc((size_t)N_NODES * 128 * 4);
    float*        h2      = h;   // h dead after agg1

    int nblk_nodes = (N_NODES + 255) / 256;   // 196
    int nblk_edges4 = EDGE_T / 256;           // 1563

    hipMemsetAsync(outdeg, 0, (size_t)N_NODES * 4, stream);
    hipMemsetAsync(indeg,  0, (size_t)N_NODES * 4, stream);

    gcn_degi_kernel<<<nblk_edges4, 256, 0, stream>>>(dst, indeg);
    gcn_scan1_kernel<<<nblk_nodes, 256, 0, stream>>>(indeg, row_ptr, blksum, N_NODES);
    gcn_scan2_kernel<<<1, 256, 0, stream>>>(blksum, blkoff, nblk_nodes);
    gcn_scan3_kernel<<<nblk_nodes, 256, 0, stream>>>(row_ptr, cursor, blkoff, N_NODES);
    gcn_fill_kernel<<<nblk_edges4, 256, 0, stream>>>(src, dst, cursor, outdeg, csr);
    gcn_norm_kernel<<<nblk_nodes, 256, 0, stream>>>(outdeg, indeg, on, inn);

    int ntiles = (N_NODES + 63) / 64;         // 782
    gcn_gemm1_kernel<<<ntiles * 2, 256, 0, stream>>>(x, on, W1, h);
    gcn_agg1_kernel<<<N_NODES, 128, 0, stream>>>(h, csr, row_ptr, inn, b1, h1);
    gcn_gemm2_kernel<<<ntiles, 256, 0, stream>>>(h1, on, W2, h2);
    gcn_agg2_kernel<<<N_NODES, 64, 0, stream>>>(h2, csr, row_ptr, inn, b2, out);
}

// Round 3
// 431.918 us; speedup vs baseline: 1.3702x; 1.0330x over previous
//
#include <hip/hip_runtime.h>
#include <cstdint>

#define N_NODES 50000
#define N_EDGES 1600000

#define SLICES 8
#define CHUNKS 256
#define EPC (N_EDGES / CHUNKS)        // 6250 edges per chunk
#define NPS (N_NODES / SLICES)        // 6250 nodes per slice

// ---------------- degree counting, XCD-slice-local atomics ----------------
__global__ void gcn_count_kernel(const int* __restrict__ src, const int* __restrict__ dst,
                                 unsigned int* __restrict__ outdeg, unsigned int* __restrict__ indeg) {
    int slice = blockIdx.x & (SLICES - 1);   // == XCD id under round-robin dispatch
    int chunk = blockIdx.x >> 3;
    int lo = slice * NPS, hi = lo + NPS;
    int base = chunk * EPC;
    for (int i = threadIdx.x; i < EPC; i += 256) {
        int s = src[base + i];
        int d = dst[base + i];
        if (s >= lo && s < hi) atomicAdd(&outdeg[s], 1u);
        if (d >= lo && d < hi) atomicAdd(&indeg[d], 1u);
    }
}

// ---------------- exclusive scan ----------------
__global__ void gcn_scan1_kernel(const unsigned int* __restrict__ in, unsigned int* __restrict__ out,
                                 unsigned int* __restrict__ blk, int n) {
    __shared__ unsigned int s[256];
    int tid = threadIdx.x;
    int i = blockIdx.x * 256 + tid;
    unsigned int v = (i < n) ? in[i] : 0u;
    s[tid] = v;
    __syncthreads();
    for (int off = 1; off < 256; off <<= 1) {
        unsigned int t = (tid >= off) ? s[tid - off] : 0u;
        __syncthreads();
        s[tid] += t;
        __syncthreads();
    }
    if (i < n) out[i] = s[tid] - v;  // exclusive
    if (tid == 255) blk[blockIdx.x] = s[255];
}

__global__ void gcn_scan2_kernel(const unsigned int* __restrict__ blk, unsigned int* __restrict__ blkoff, int nblk) {
    __shared__ unsigned int s[256];
    int tid = threadIdx.x;
    unsigned int v = (tid < nblk) ? blk[tid] : 0u;
    s[tid] = v;
    __syncthreads();
    for (int off = 1; off < 256; off <<= 1) {
        unsigned int t = (tid >= off) ? s[tid - off] : 0u;
        __syncthreads();
        s[tid] += t;
        __syncthreads();
    }
    blkoff[tid] = s[tid] - v;
}

// scan3 + norm fused
__global__ void gcn_scan3_kernel(unsigned int* __restrict__ row_ptr, unsigned int* __restrict__ cursor,
                                 const unsigned int* __restrict__ blkoff,
                                 const unsigned int* __restrict__ outdeg,
                                 const unsigned int* __restrict__ indeg,
                                 float* __restrict__ on, float* __restrict__ inn, int n) {
    int i = blockIdx.x * 256 + threadIdx.x;
    if (i < n) {
        unsigned int r = row_ptr[i] + blkoff[blockIdx.x];
        row_ptr[i] = r;
        cursor[i] = r;
        unsigned int od = outdeg[i]; if (od < 1u) od = 1u;
        unsigned int id = indeg[i];  if (id < 1u) id = 1u;
        on[i]  = rsqrtf((float)od);
        inn[i] = rsqrtf((float)id);
    }
    if (i == 0) row_ptr[n] = N_EDGES;
}

// ---------------- CSR fill, XCD-slice-local atomics + stores ----------------
__global__ void gcn_fill_kernel(const int* __restrict__ src, const int* __restrict__ dst,
                                unsigned int* __restrict__ cursor, int* __restrict__ csr_src) {
    int slice = blockIdx.x & (SLICES - 1);
    int chunk = blockIdx.x >> 3;
    int lo = slice * NPS, hi = lo + NPS;
    int base = chunk * EPC;
    for (int i = threadIdx.x; i < EPC; i += 256) {
        int d = dst[base + i];
        if (d >= lo && d < hi) {
            int s = src[base + i];
            unsigned int pos = atomicAdd(&cursor[d], 1u);
            csr_src[pos] = s;
        }
    }
}

// ---------------- GEMM helpers ----------------
#define FMA4(A, S, WV) { (A).x += (S)*(WV).x; (A).y += (S)*(WV).y; (A).z += (S)*(WV).z; (A).w += (S)*(WV).w; }

// GEMM1: h = (x * on[:,None]) @ W1  (50000x128 @ 128x128), j-half per block
__global__ __launch_bounds__(256, 4) void gcn_gemm1_kernel(
        const float* __restrict__ x, const float* __restrict__ on,
        const float* __restrict__ W, float* __restrict__ h) {
    __shared__ float4 Ws[128 * 16];      // 32 KiB: half of W's columns
    int tid = threadIdx.x;
    int tile = blockIdx.x >> 1, half = blockIdx.x & 1;
    for (int i = tid; i < 128 * 16; i += 256) {
        int k = i >> 4, q = i & 15;
        Ws[i] = ((const float4*)W)[k * 32 + half * 16 + q];
    }
    __syncthreads();

    int jg = tid & 15;        // float4 group within the 64-output half
    int ns = tid >> 4;        // 0..15
    int n0 = tile * 64 + ns * 4;

    float sc[4]; bool val[4];
    float4 acc[4];
    #pragma unroll
    for (int i = 0; i < 4; ++i) {
        int n = n0 + i; val[i] = (n < N_NODES);
        sc[i] = val[i] ? on[n] : 0.f;
        acc[i] = float4{0.f, 0.f, 0.f, 0.f};
    }

    const float4* xv4 = (const float4*)x;
    float4 xc[4], wc[4], xn[4], wn[4];
    #pragma unroll
    for (int i = 0; i < 4; ++i)
        xc[i] = val[i] ? xv4[(size_t)(n0 + i) * 32] : float4{0.f, 0.f, 0.f, 0.f};
    #pragma unroll
    for (int t = 0; t < 4; ++t) wc[t] = Ws[t * 16 + jg];

    for (int kc = 0; kc < 32; ++kc) {
        if (kc < 31) {
            #pragma unroll
            for (int i = 0; i < 4; ++i)
                xn[i] = val[i] ? xv4[(size_t)(n0 + i) * 32 + kc + 1] : float4{0.f, 0.f, 0.f, 0.f};
            #pragma unroll
            for (int t = 0; t < 4; ++t) wn[t] = Ws[(kc * 4 + 4 + t) * 16 + jg];
        }
        #pragma unroll
        for (int i = 0; i < 4; ++i) {
            FMA4(acc[i], xc[i].x, wc[0]);
            FMA4(acc[i], xc[i].y, wc[1]);
            FMA4(acc[i], xc[i].z, wc[2]);
            FMA4(acc[i], xc[i].w, wc[3]);
        }
        #pragma unroll
        for (int i = 0; i < 4; ++i) xc[i] = xn[i];
        #pragma unroll
        for (int t = 0; t < 4; ++t) wc[t] = wn[t];
    }
    #pragma unroll
    for (int i = 0; i < 4; ++i) {
        if (val[i]) {
            acc[i].x *= sc[i]; acc[i].y *= sc[i]; acc[i].z *= sc[i]; acc[i].w *= sc[i];
            ((float4*)h)[(size_t)(n0 + i) * 32 + half * 16 + jg] = acc[i];
        }
    }
}

// GEMM2: h2 = (h1 * on[:,None]) @ W2  (50000x128 @ 128x64)
__global__ __launch_bounds__(256, 4) void gcn_gemm2_kernel(
        const float* __restrict__ h1, const float* __restrict__ on,
        const float* __restrict__ W, float* __restrict__ h2) {
    __shared__ float4 Ws[128 * 16];      // 32 KiB: all of W2
    int tid = threadIdx.x;
    int tile = blockIdx.x;
    for (int i = tid; i < 128 * 16; i += 256) Ws[i] = ((const float4*)W)[i];
    __syncthreads();

    int jg = tid & 15;        // float4 group over 64 outputs
    int ns = tid >> 4;        // 0..15
    int n0 = tile * 64 + ns * 4;

    float sc[4]; bool val[4];
    float4 acc[4];
    #pragma unroll
    for (int i = 0; i < 4; ++i) {
        int n = n0 + i; val[i] = (n < N_NODES);
        sc[i] = val[i] ? on[n] : 0.f;
        acc[i] = float4{0.f, 0.f, 0.f, 0.f};
    }

    const float4* xv4 = (const float4*)h1;
    float4 xc[4], wc[4], xn[4], wn[4];
    #pragma unroll
    for (int i = 0; i < 4; ++i)
        xc[i] = val[i] ? xv4[(size_t)(n0 + i) * 32] : float4{0.f, 0.f, 0.f, 0.f};
    #pragma unroll
    for (int t = 0; t < 4; ++t) wc[t] = Ws[t * 16 + jg];

    for (int kc = 0; kc < 32; ++kc) {
        if (kc < 31) {
            #pragma unroll
            for (int i = 0; i < 4; ++i)
                xn[i] = val[i] ? xv4[(size_t)(n0 + i) * 32 + kc + 1] : float4{0.f, 0.f, 0.f, 0.f};
            #pragma unroll
            for (int t = 0; t < 4; ++t) wn[t] = Ws[(kc * 4 + 4 + t) * 16 + jg];
        }
        #pragma unroll
        for (int i = 0; i < 4; ++i) {
            FMA4(acc[i], xc[i].x, wc[0]);
            FMA4(acc[i], xc[i].y, wc[1]);
            FMA4(acc[i], xc[i].z, wc[2]);
            FMA4(acc[i], xc[i].w, wc[3]);
        }
        #pragma unroll
        for (int i = 0; i < 4; ++i) xc[i] = xn[i];
        #pragma unroll
        for (int t = 0; t < 4; ++t) wc[t] = wn[t];
    }
    #pragma unroll
    for (int i = 0; i < 4; ++i) {
        if (val[i]) {
            acc[i].x *= sc[i]; acc[i].y *= sc[i]; acc[i].z *= sc[i]; acc[i].w *= sc[i];
            ((float4*)h2)[(size_t)(n0 + i) * 16 + jg] = acc[i];
        }
    }
}

// ---------------- agg1: h1 = relu(segsum(h[src]) * inn + b1) ----------------
__global__ void gcn_agg1_kernel(const float* __restrict__ h, const int* __restrict__ csr,
                                const unsigned int* __restrict__ row_ptr,
                                const float* __restrict__ inn, const float* __restrict__ b1,
                                float* __restrict__ h1) {
    int n = blockIdx.x;
    int tid = threadIdx.x;  // 128
    unsigned int beg = row_ptr[n], end = row_ptr[n + 1];
    __shared__ int es[128];
    float acc = 0.f;
    for (unsigned int base = beg; base < end; base += 128) {
        unsigned int cnt = end - base; if (cnt > 128u) cnt = 128u;
        if (tid < (int)cnt) es[tid] = csr[base + tid];
        __syncthreads();
        for (unsigned int i = 0; i < cnt; ++i) {
            acc += h[(size_t)es[i] * 128 + tid];
        }
        __syncthreads();
    }
    float v = acc * inn[n] + b1[tid];
    h1[(size_t)n * 128 + tid] = fmaxf(v, 0.f);
}

// ---------------- agg2: out = segsum(h2[src]) * inn + b2 ----------------
__global__ void gcn_agg2_kernel(const float* __restrict__ h2, const int* __restrict__ csr,
                                const unsigned int* __restrict__ row_ptr,
                                const float* __restrict__ inn, const float* __restrict__ b2,
                                float* __restrict__ out) {
    int n = blockIdx.x;
    int tid = threadIdx.x;  // 64
    unsigned int beg = row_ptr[n], end = row_ptr[n + 1];
    __shared__ int es[64];
    float acc = 0.f;
    for (unsigned int base = beg; base < end; base += 64) {
        unsigned int cnt = end - base; if (cnt > 64u) cnt = 64u;
        if (tid < (int)cnt) es[tid] = csr[base + tid];
        __syncthreads();
        for (unsigned int i = 0; i < cnt; ++i) {
            acc += h2[(size_t)es[i] * 64 + tid];
        }
        __syncthreads();
    }
    out[(size_t)n * 64 + tid] = acc * inn[n] + b2[tid];
}

extern "C" void kernel_launch(void* const* d_in, const int* in_sizes, int n_in,
                              void* d_out, int out_size, void* d_ws, size_t ws_size,
                              hipStream_t stream) {
    const float* x  = (const float*)d_in[0];
    const float* W1 = (const float*)d_in[1];
    const float* b1 = (const float*)d_in[2];
    const float* W2 = (const float*)d_in[3];
    const float* b2 = (const float*)d_in[4];
    const int*   src = (const int*)d_in[5];
    const int*   dst = (const int*)d_in[6];
    float* out = (float*)d_out;

    char* ws = (char*)d_ws;
    size_t off = 0;
    auto alloc = [&](size_t bytes) -> void* {
        void* p = ws + off;
        off += (bytes + 255) & ~(size_t)255;
        return p;
    };

    unsigned int* outdeg  = (unsigned int*)alloc((size_t)N_NODES * 4);
    unsigned int* indeg   = (unsigned int*)alloc((size_t)N_NODES * 4);
    float*        on      = (float*)alloc((size_t)N_NODES * 4);
    float*        inn     = (float*)alloc((size_t)N_NODES * 4);
    unsigned int* row_ptr = (unsigned int*)alloc((size_t)(N_NODES + 1) * 4);
    unsigned int* cursor  = (unsigned int*)alloc((size_t)N_NODES * 4);
    unsigned int* blksum  = (unsigned int*)alloc(256 * 4);
    unsigned int* blkoff  = (unsigned int*)alloc(256 * 4);
    int*          csr     = (int*)alloc((size_t)N_EDGES * 4);
    float*        h       = (float*)alloc((size_t)N_NODES * 128 * 4);   // reused as h2
    float*        h1      = (float*)alloc((size_t)N_NODES * 128 * 4);
    float*        h2      = h;   // h dead after agg1

    int nblk_nodes = (N_NODES + 255) / 256;   // 196

    hipMemsetAsync(outdeg, 0, (size_t)N_NODES * 4, stream);
    hipMemsetAsync(indeg,  0, (size_t)N_NODES * 4, stream);

    gcn_count_kernel<<<SLICES * CHUNKS, 256, 0, stream>>>(src, dst, outdeg, indeg);
    gcn_scan1_kernel<<<nblk_nodes, 256, 0, stream>>>(indeg, row_ptr, blksum, N_NODES);
    gcn_scan2_kernel<<<1, 256, 0, stream>>>(blksum, blkoff, nblk_nodes);
    gcn_scan3_kernel<<<nblk_nodes, 256, 0, stream>>>(row_ptr, cursor, blkoff, outdeg, indeg, on, inn, N_NODES);
    gcn_fill_kernel<<<SLICES * CHUNKS, 256, 0, stream>>>(src, dst, cursor, csr);

    int ntiles = (N_NODES + 63) / 64;         // 782
    gcn_gemm1_kernel<<<ntiles * 2, 256, 0, stream>>>(x, on, W1, h);
    gcn_agg1_kernel<<<N_NODES, 128, 0, stream>>>(h, csr, row_ptr, inn, b1, h1);
    gcn_gemm2_kernel<<<ntiles, 256, 0, stream>>>(h1, on, W2, h2);
    gcn_agg2_kernel<<<N_NODES, 64, 0, stream>>>(h2, csr, row_ptr, inn, b2, out);
}